// Round 1
// baseline (1062.089 us; speedup 1.0000x reference)
//
#include <hip/hip_runtime.h>
#include <hip/hip_bf16.h>

// ---- problem constants ----
#define BB    16
#define TT    1024
#define MTOK  (BB*TT)     // 16384 tokens
#define IDIM_ 345
#define KPAD  352         // 345 padded to /32
#define LL    4
#define DD_   256
#define HH    4
#define DKK   64
#define FF_   1024
#define EPS_  1e-5f

typedef __bf16 bf16;
typedef bf16 bf16x8 __attribute__((ext_vector_type(8)));
typedef float f32x4 __attribute__((ext_vector_type(4)));

static __device__ __forceinline__ bf16x8 ld_bf8(const bf16* p) {
  return *reinterpret_cast<const bf16x8*>(p);
}

// ---- conversion kernels ----
// src [rows, K] f32 -> dst [rows, Kp] bf16 zero-padded
__global__ void k_convert_pad(const float* __restrict__ src, bf16* __restrict__ dst,
                              int rows, int K, int Kp) {
  int idx = blockIdx.x * 256 + threadIdx.x;
  if (idx >= rows * Kp) return;
  int r = idx / Kp, c = idx % Kp;
  dst[idx] = (c < K) ? (bf16)src[(long)r * K + c] : (bf16)0.f;
}

// src [K, N] f32 -> dst [N, Kp] bf16 (transposed, zero-padded along K)
__global__ void k_wt_convert(const float* __restrict__ src, bf16* __restrict__ dst,
                             int K, int N, int Kp) {
  int idx = blockIdx.x * 256 + threadIdx.x;
  if (idx >= N * Kp) return;
  int n = idx / Kp, kk = idx % Kp;
  dst[idx] = (kk < K) ? (bf16)src[(long)kk * N + n] : (bf16)0.f;
}

// ---- LayerNorm: one wave per row of 256; writes f32 and/or bf16 ----
__global__ __launch_bounds__(256)
void k_ln(const float* __restrict__ in, float* __restrict__ outf,
          bf16* __restrict__ outb, const float* __restrict__ s,
          const float* __restrict__ b) {
  const int wave = threadIdx.x >> 6, lane = threadIdx.x & 63;
  const int row = blockIdx.x * 4 + wave;
  const float4 xv = *reinterpret_cast<const float4*>(in + (long)row * DD_ + lane * 4);
  float sum = xv.x + xv.y + xv.z + xv.w;
  #pragma unroll
  for (int off = 1; off < 64; off <<= 1) sum += __shfl_xor(sum, off);
  const float m = sum * (1.f / DD_);
  const float dx = xv.x - m, dy = xv.y - m, dz = xv.z - m, dw = xv.w - m;
  float ss = dx*dx + dy*dy + dz*dz + dw*dw;
  #pragma unroll
  for (int off = 1; off < 64; off <<= 1) ss += __shfl_xor(ss, off);
  const float inv = rsqrtf(ss * (1.f / DD_) + EPS_);
  const float4 sv = *reinterpret_cast<const float4*>(s + lane * 4);
  const float4 bv = *reinterpret_cast<const float4*>(b + lane * 4);
  float4 y;
  y.x = dx * inv * sv.x + bv.x;
  y.y = dy * inv * sv.y + bv.y;
  y.z = dz * inv * sv.z + bv.z;
  y.w = dw * inv * sv.w + bv.w;
  if (outf) *reinterpret_cast<float4*>(outf + (long)row * DD_ + lane * 4) = y;
  if (outb) {
    unsigned u0 = __builtin_bit_cast(unsigned short, (bf16)y.x);
    unsigned u1 = __builtin_bit_cast(unsigned short, (bf16)y.y);
    unsigned u2 = __builtin_bit_cast(unsigned short, (bf16)y.z);
    unsigned u3 = __builtin_bit_cast(unsigned short, (bf16)y.w);
    uint2 pk; pk.x = u0 | (u1 << 16); pk.y = u2 | (u3 << 16);
    *reinterpret_cast<uint2*>(outb + (long)row * DD_ + lane * 4) = pk;
  }
}

// ---- GEMM: C[M,N] = A[M,K](bf16) @ W[K,N] (given as Wt[N,K] bf16) ----
// EPI 0: out bf16 = acc + bias
// EPI 1: out bf16 = relu(acc + bias)
// EPI 2: out f32  = resid + acc + bias   (resid may be null)
// 128x128 tile, BK=32, 4 waves each computing 64x64 (4x4 frags of 16x16x32).
template<int EPI>
__global__ __launch_bounds__(256)
void k_gemm(const bf16* __restrict__ A, const bf16* __restrict__ Wt,
            const float* __restrict__ bias, const float* __restrict__ resid,
            void* __restrict__ out, int M, int N, int K) {
  __shared__ alignas(16) bf16 As[128 * 32];
  __shared__ alignas(16) bf16 Bs[128 * 32];
  const int t = threadIdx.x;
  const int lane = t & 63, wid = t >> 6;
  const int wr = wid >> 1, wc = wid & 1;
  const int mbase = blockIdx.y * 128, nbase = blockIdx.x * 128;
  const int g = lane >> 4, c = lane & 15;
  const int sr = t >> 2;            // staging row (0..63), two passes of 64 rows
  const int sk = (t & 3) * 8;       // staging k offset

  f32x4 acc[4][4] = {};

  const int nk = K >> 5;
  for (int kt = 0; kt < nk; ++kt) {
    const int k0 = kt * 32;
    // global loads to regs (before barrier; overlap with previous compute)
    int4 a0 = *reinterpret_cast<const int4*>(A + (long)(mbase + sr) * K + k0 + sk);
    int4 a1 = *reinterpret_cast<const int4*>(A + (long)(mbase + 64 + sr) * K + k0 + sk);
    int4 b0 = *reinterpret_cast<const int4*>(Wt + (long)(nbase + sr) * K + k0 + sk);
    int4 b1 = *reinterpret_cast<const int4*>(Wt + (long)(nbase + 64 + sr) * K + k0 + sk);
    __syncthreads();  // previous iteration's reads done before overwrite
    *reinterpret_cast<int4*>(As + sr * 32 + sk) = a0;
    *reinterpret_cast<int4*>(As + (64 + sr) * 32 + sk) = a1;
    *reinterpret_cast<int4*>(Bs + sr * 32 + sk) = b0;
    *reinterpret_cast<int4*>(Bs + (64 + sr) * 32 + sk) = b1;
    __syncthreads();

    bf16x8 af[4], bfr[4];
    #pragma unroll
    for (int mi = 0; mi < 4; mi++) af[mi]  = ld_bf8(As + (wr * 64 + mi * 16 + c) * 32 + g * 8);
    #pragma unroll
    for (int ni = 0; ni < 4; ni++) bfr[ni] = ld_bf8(Bs + (wc * 64 + ni * 16 + c) * 32 + g * 8);
    #pragma unroll
    for (int mi = 0; mi < 4; mi++)
      #pragma unroll
      for (int ni = 0; ni < 4; ni++)
        acc[mi][ni] = __builtin_amdgcn_mfma_f32_16x16x32_bf16(af[mi], bfr[ni], acc[mi][ni], 0, 0, 0);
  }

  // epilogue: C row = (lane>>4)*4 + reg, col = lane&15 (measured layout)
  #pragma unroll
  for (int mi = 0; mi < 4; mi++) {
    #pragma unroll
    for (int ni = 0; ni < 4; ni++) {
      const int colg = nbase + wc * 64 + ni * 16 + c;
      const float bv = bias ? bias[colg] : 0.f;
      #pragma unroll
      for (int j = 0; j < 4; j++) {
        const int rowg = mbase + wr * 64 + mi * 16 + g * 4 + j;
        float v = acc[mi][ni][j] + bv;
        if constexpr (EPI == 0) {
          ((bf16*)out)[(long)rowg * N + colg] = (bf16)v;
        } else if constexpr (EPI == 1) {
          ((bf16*)out)[(long)rowg * N + colg] = (bf16)fmaxf(v, 0.f);
        } else {
          float r = resid ? resid[(long)rowg * N + colg] : 0.f;
          ((float*)out)[(long)rowg * N + colg] = r + v;
        }
      }
    }
  }
}

// ---- flash attention: one block per (b,h, 64-row q tile) ----
// q,k,v,o: [MTOK, 256] bf16, head h occupies cols h*64..h*64+63
__global__ __launch_bounds__(256)
void k_attn(const bf16* __restrict__ q, const bf16* __restrict__ k,
            const bf16* __restrict__ v, bf16* __restrict__ o) {
  __shared__ alignas(16) bf16 Qs[64 * 64];
  __shared__ alignas(16) bf16 Ks[64 * 64];
  __shared__ alignas(16) bf16 Vt[64 * 64];   // transposed: [dk][kv]
  __shared__ alignas(16) bf16 Ps[4 * 16 * 64]; // per-wave P tile [16 q rows][64 kv]
  const int t = threadIdx.x, lane = t & 63, w = t >> 6;
  const int g = lane >> 4, c = lane & 15;
  const int bh = blockIdx.y;            // b*H + h
  const int b = bh >> 2, h = bh & 3;
  const int qt = blockIdx.x;            // q tile 0..15
  const long base = ((long)b * TT) * DD_ + h * DKK;
  const float scale = 0.125f;           // 1/sqrt(64)

  // stage Q tile [64][64]
  #pragma unroll
  for (int p = 0; p < 2; p++) {
    int flat = p * 2048 + t * 8;
    int r = flat >> 6, d0 = flat & 63;
    *reinterpret_cast<int4*>(Qs + flat) =
        *reinterpret_cast<const int4*>(q + base + (long)(qt * 64 + r) * DD_ + d0);
  }

  f32x4 oacc[4] = {};
  float mrun[4], lrun[4];
  #pragma unroll
  for (int j = 0; j < 4; j++) { mrun[j] = -1e30f; lrun[j] = 0.f; }

  for (int jt = 0; jt < 16; ++jt) {
    __syncthreads();  // previous iteration's K/V reads done
    #pragma unroll
    for (int p = 0; p < 2; p++) {
      int flat = p * 2048 + t * 8;
      int r = flat >> 6, d0 = flat & 63;
      *reinterpret_cast<int4*>(Ks + flat) =
          *reinterpret_cast<const int4*>(k + base + (long)(jt * 64 + r) * DD_ + d0);
      union { int4 i4; bf16 h8[8]; } u;
      u.i4 = *reinterpret_cast<const int4*>(v + base + (long)(jt * 64 + r) * DD_ + d0);
      #pragma unroll
      for (int i = 0; i < 8; i++) Vt[(d0 + i) * 64 + r] = u.h8[i];
    }
    __syncthreads();

    // S = Q K^T : wave w handles q rows w*16..w*16+15, all 64 kv cols
    f32x4 sacc[4] = {};
    bf16x8 aq0 = ld_bf8(Qs + (w * 16 + c) * 64 + g * 8);
    bf16x8 aq1 = ld_bf8(Qs + (w * 16 + c) * 64 + 32 + g * 8);
    #pragma unroll
    for (int ni = 0; ni < 4; ni++) {
      bf16x8 bk0 = ld_bf8(Ks + (ni * 16 + c) * 64 + g * 8);
      bf16x8 bk1 = ld_bf8(Ks + (ni * 16 + c) * 64 + 32 + g * 8);
      sacc[ni] = __builtin_amdgcn_mfma_f32_16x16x32_bf16(aq0, bk0, sacc[ni], 0, 0, 0);
      sacc[ni] = __builtin_amdgcn_mfma_f32_16x16x32_bf16(aq1, bk1, sacc[ni], 0, 0, 0);
    }

    // online softmax (rows: g*4+j within wave's 16; cols: ni*16+c)
    float al[4];
    #pragma unroll
    for (int j = 0; j < 4; j++) {
      float m0 = fmaxf(fmaxf(sacc[0][j], sacc[1][j]), fmaxf(sacc[2][j], sacc[3][j]));
      #pragma unroll
      for (int off = 1; off < 16; off <<= 1) m0 = fmaxf(m0, __shfl_xor(m0, off));
      float mn = fmaxf(mrun[j], m0);
      al[j] = __expf(scale * (mrun[j] - mn));
      mrun[j] = mn;
    }
    float rs[4] = {0.f, 0.f, 0.f, 0.f};
    #pragma unroll
    for (int ni = 0; ni < 4; ni++) {
      #pragma unroll
      for (int j = 0; j < 4; j++) {
        float pv = __expf(scale * (sacc[ni][j] - mrun[j]));
        rs[j] += pv;
        Ps[w * 1024 + (g * 4 + j) * 64 + ni * 16 + c] = (bf16)pv;
      }
    }
    #pragma unroll
    for (int j = 0; j < 4; j++) {
      #pragma unroll
      for (int off = 1; off < 16; off <<= 1) rs[j] += __shfl_xor(rs[j], off);
      lrun[j] = lrun[j] * al[j] + rs[j];
    }
    #pragma unroll
    for (int nd = 0; nd < 4; nd++)
      #pragma unroll
      for (int j = 0; j < 4; j++) oacc[nd][j] *= al[j];

    // O += P V  (A = P[qrow][kv] from Ps, B = V[kv][dk] via Vt[dk][kv])
    #pragma unroll
    for (int kk = 0; kk < 2; kk++) {
      bf16x8 ap = ld_bf8(Ps + w * 1024 + c * 64 + kk * 32 + g * 8);
      #pragma unroll
      for (int nd = 0; nd < 4; nd++) {
        bf16x8 bv_ = ld_bf8(Vt + (nd * 16 + c) * 64 + kk * 32 + g * 8);
        oacc[nd] = __builtin_amdgcn_mfma_f32_16x16x32_bf16(ap, bv_, oacc[nd], 0, 0, 0);
      }
    }
  }

  // write O (bf16), normalized by row sums
  #pragma unroll
  for (int nd = 0; nd < 4; nd++) {
    #pragma unroll
    for (int j = 0; j < 4; j++) {
      int row = qt * 64 + w * 16 + g * 4 + j;
      int col = nd * 16 + c;
      o[base + (long)row * DD_ + col] = (bf16)(oacc[nd][j] / lrun[j]);
    }
  }
}

// ---- host ----
extern "C" void kernel_launch(void* const* d_in, const int* in_sizes, int n_in,
                              void* d_out, int out_size, void* d_ws, size_t ws_size,
                              hipStream_t stream) {
  const float* x     = (const float*)d_in[0];
  const float* Win   = (const float*)d_in[2];
  const float* b_in  = (const float*)d_in[3];
  const float* ln1_s = (const float*)d_in[4];
  const float* ln1_b = (const float*)d_in[5];
  const float* Wq    = (const float*)d_in[6];
  const float* bq    = (const float*)d_in[7];
  const float* Wk    = (const float*)d_in[8];
  const float* bk    = (const float*)d_in[9];
  const float* Wv    = (const float*)d_in[10];
  const float* bv    = (const float*)d_in[11];
  const float* Wo    = (const float*)d_in[12];
  const float* bo    = (const float*)d_in[13];
  const float* ln2_s = (const float*)d_in[14];
  const float* ln2_b = (const float*)d_in[15];
  const float* W1    = (const float*)d_in[16];
  const float* b1    = (const float*)d_in[17];
  const float* W2    = (const float*)d_in[18];
  const float* b2    = (const float*)d_in[19];
  const float* lno_s = (const float*)d_in[20];
  const float* lno_b = (const float*)d_in[21];
  float* out = (float*)d_out;

  char* ws = (char*)d_ws;
  size_t off = 0;
  auto alloc = [&](size_t bytes) -> void* {
    void* p = ws + off; off += (bytes + 255) & ~(size_t)255; return p;
  };
  float* e   = (float*)alloc((size_t)MTOK * DD_ * 4);
  bf16* e_bf = (bf16*)alloc((size_t)MTOK * DD_ * 2);
  bf16* x_bf = (bf16*)alloc((size_t)MTOK * KPAD * 2);
  bf16* qb   = (bf16*)alloc((size_t)MTOK * DD_ * 2);
  bf16* kb   = (bf16*)alloc((size_t)MTOK * DD_ * 2);
  bf16* vb   = (bf16*)alloc((size_t)MTOK * DD_ * 2);
  bf16* ob   = (bf16*)alloc((size_t)MTOK * DD_ * 2);
  bf16* hb   = (bf16*)alloc((size_t)MTOK * FF_ * 2);
  bf16* Wint = (bf16*)alloc((size_t)DD_ * KPAD * 2);
  bf16* Wqt  = (bf16*)alloc((size_t)LL * DD_ * DD_ * 2);
  bf16* Wkt  = (bf16*)alloc((size_t)LL * DD_ * DD_ * 2);
  bf16* Wvt  = (bf16*)alloc((size_t)LL * DD_ * DD_ * 2);
  bf16* Wot  = (bf16*)alloc((size_t)LL * DD_ * DD_ * 2);
  bf16* W1t  = (bf16*)alloc((size_t)LL * DD_ * FF_ * 2);
  bf16* W2t  = (bf16*)alloc((size_t)LL * FF_ * DD_ * 2);

  const int DDW = DD_ * DD_;      // 65536
  const int DFF = DD_ * FF_;      // 262144

  // conversions
  k_convert_pad<<<(MTOK * KPAD + 255) / 256, 256, 0, stream>>>(x, x_bf, MTOK, IDIM_, KPAD);
  k_wt_convert<<<(DD_ * KPAD + 255) / 256, 256, 0, stream>>>(Win, Wint, IDIM_, DD_, KPAD);
  for (int i = 0; i < LL; i++) {
    k_wt_convert<<<(DDW + 255) / 256, 256, 0, stream>>>(Wq + (long)i * DDW, Wqt + (long)i * DDW, DD_, DD_, DD_);
    k_wt_convert<<<(DDW + 255) / 256, 256, 0, stream>>>(Wk + (long)i * DDW, Wkt + (long)i * DDW, DD_, DD_, DD_);
    k_wt_convert<<<(DDW + 255) / 256, 256, 0, stream>>>(Wv + (long)i * DDW, Wvt + (long)i * DDW, DD_, DD_, DD_);
    k_wt_convert<<<(DDW + 255) / 256, 256, 0, stream>>>(Wo + (long)i * DDW, Wot + (long)i * DDW, DD_, DD_, DD_);
    k_wt_convert<<<(DFF + 255) / 256, 256, 0, stream>>>(W1 + (long)i * DFF, W1t + (long)i * DFF, DD_, FF_, DD_);
    k_wt_convert<<<(DFF + 255) / 256, 256, 0, stream>>>(W2 + (long)i * DFF, W2t + (long)i * DFF, FF_, DD_, FF_);
  }

  dim3 blk(256);
  // input projection: e = x @ Win + b_in
  k_gemm<2><<<dim3(2, 128), blk, 0, stream>>>(x_bf, Wint, b_in, nullptr, e, MTOK, DD_, KPAD);

  for (int i = 0; i < LL; i++) {
    k_ln<<<MTOK / 4, 256, 0, stream>>>(e, e, e_bf, ln1_s + i * DD_, ln1_b + i * DD_);
    k_gemm<0><<<dim3(2, 128), blk, 0, stream>>>(e_bf, Wqt + (long)i * DDW, bq + i * DD_, nullptr, qb, MTOK, DD_, DD_);
    k_gemm<0><<<dim3(2, 128), blk, 0, stream>>>(e_bf, Wkt + (long)i * DDW, bk + i * DD_, nullptr, kb, MTOK, DD_, DD_);
    k_gemm<0><<<dim3(2, 128), blk, 0, stream>>>(e_bf, Wvt + (long)i * DDW, bv + i * DD_, nullptr, vb, MTOK, DD_, DD_);
    k_attn<<<dim3(16, 64), blk, 0, stream>>>(qb, kb, vb, ob);
    k_gemm<2><<<dim3(2, 128), blk, 0, stream>>>(ob, Wot + (long)i * DDW, bo + i * DD_, e, e, MTOK, DD_, DD_);
    k_ln<<<MTOK / 4, 256, 0, stream>>>(e, e, e_bf, ln2_s + i * DD_, ln2_b + i * DD_);
    k_gemm<1><<<dim3(8, 128), blk, 0, stream>>>(e_bf, W1t + (long)i * DFF, b1 + i * FF_, nullptr, hb, MTOK, FF_, DD_);
    k_gemm<2><<<dim3(2, 128), blk, 0, stream>>>(hb, W2t + (long)i * DFF, b2 + i * DD_, e, e, MTOK, DD_, FF_);
  }
  k_ln<<<MTOK / 4, 256, 0, stream>>>(e, out, nullptr, lno_s, lno_b);
}

// Round 2
// 713.167 us; speedup vs baseline: 1.4893x; 1.4893x over previous
//
#include <hip/hip_runtime.h>
#include <hip/hip_bf16.h>

// ---- problem constants ----
#define BB    16
#define TT    1024
#define MTOK  (BB*TT)     // 16384 tokens
#define IDIM_ 345
#define KPAD  352
#define LL    4
#define DD_   256
#define FF_   1024
#define EPS_  1e-5f

typedef __bf16 bf16;
typedef bf16 bf16x8 __attribute__((ext_vector_type(8)));
typedef float f32x4 __attribute__((ext_vector_type(4)));

static __device__ __forceinline__ f32x4 MFMA(bf16x8 a, bf16x8 b, f32x4 c) {
  return __builtin_amdgcn_mfma_f32_16x16x32_bf16(a, b, c, 0, 0, 0);
}
static __device__ __forceinline__ unsigned bfbits(float x) {
  return (unsigned)__builtin_bit_cast(unsigned short, (bf16)x);
}
static __device__ __forceinline__ bf16x8 ld_bf8(const void* p) {
  return *reinterpret_cast<const bf16x8*>(p);
}

// ---- conversion kernels ----
__global__ void k_convert_pad(const float* __restrict__ src, bf16* __restrict__ dst,
                              int rows, int K, int Kp) {
  int idx = blockIdx.x * 256 + threadIdx.x;
  if (idx >= rows * Kp) return;
  int r = idx / Kp, c = idx % Kp;
  dst[idx] = (c < K) ? (bf16)src[(long)r * K + c] : (bf16)0.f;
}

__global__ void k_wt_convert(const float* __restrict__ src, bf16* __restrict__ dst,
                             int K, int N, int Kp) {
  int idx = blockIdx.x * 256 + threadIdx.x;
  if (idx >= N * Kp) return;
  int n = idx / Kp, kk = idx % Kp;
  dst[idx] = (kk < K) ? (bf16)src[(long)kk * N + n] : (bf16)0.f;
}

// all per-layer weights: [K,N] f32 -> [N,K] bf16, QKV fused into Wqkvt [768][256]
__global__ void k_wt_all(const float* __restrict__ Wq, const float* __restrict__ Wk,
                         const float* __restrict__ Wv, const float* __restrict__ Wo,
                         const float* __restrict__ W1, const float* __restrict__ W2,
                         bf16* __restrict__ Wqkvt, bf16* __restrict__ Wot,
                         bf16* __restrict__ W1t, bf16* __restrict__ W2t) {
  const int s = blockIdx.y, m = s >> 2, i = s & 3;
  const int idx = blockIdx.x * 256 + threadIdx.x;
  const float* src; bf16* dst; int kb, N, cnt;
  switch (m) {
    case 0: src = Wq + (long)i*65536;  dst = Wqkvt + (long)i*196608;          kb=8;  N=256;  cnt=65536;  break;
    case 1: src = Wk + (long)i*65536;  dst = Wqkvt + (long)i*196608 + 65536;  kb=8;  N=256;  cnt=65536;  break;
    case 2: src = Wv + (long)i*65536;  dst = Wqkvt + (long)i*196608 + 131072; kb=8;  N=256;  cnt=65536;  break;
    case 3: src = Wo + (long)i*65536;  dst = Wot + (long)i*65536;             kb=8;  N=256;  cnt=65536;  break;
    case 4: src = W1 + (long)i*262144; dst = W1t + (long)i*262144;            kb=8;  N=1024; cnt=262144; break;
    default:src = W2 + (long)i*262144; dst = W2t + (long)i*262144;            kb=10; N=256;  cnt=262144; break;
  }
  if (idx >= cnt) return;
  int n = idx >> kb, kk = idx & ((1 << kb) - 1);
  dst[idx] = (bf16)src[(long)kk * N + n];
}

__global__ void k_bias_concat(const float* __restrict__ bq, const float* __restrict__ bk,
                              const float* __restrict__ bv, float* __restrict__ bqkv) {
  int idx = blockIdx.x * 256 + threadIdx.x;
  if (idx >= LL * 768) return;
  int i = idx / 768, j = idx % 768;
  float v = (j < 256) ? bq[i*256 + j] : (j < 512 ? bk[i*256 + j - 256] : bv[i*256 + j - 512]);
  bqkv[idx] = v;
}

// ---- LayerNorm: one wave per row of 256 ----
__global__ __launch_bounds__(256)
void k_ln(const float* __restrict__ in, float* __restrict__ outf,
          bf16* __restrict__ outb, const float* __restrict__ s,
          const float* __restrict__ b) {
  const int wave = threadIdx.x >> 6, lane = threadIdx.x & 63;
  const int row = blockIdx.x * 4 + wave;
  const float4 xv = *reinterpret_cast<const float4*>(in + (long)row * DD_ + lane * 4);
  float sum = xv.x + xv.y + xv.z + xv.w;
  #pragma unroll
  for (int off = 1; off < 64; off <<= 1) sum += __shfl_xor(sum, off);
  const float m = sum * (1.f / DD_);
  const float dx = xv.x - m, dy = xv.y - m, dz = xv.z - m, dw = xv.w - m;
  float ss = dx*dx + dy*dy + dz*dz + dw*dw;
  #pragma unroll
  for (int off = 1; off < 64; off <<= 1) ss += __shfl_xor(ss, off);
  const float inv = rsqrtf(ss * (1.f / DD_) + EPS_);
  const float4 sv = *reinterpret_cast<const float4*>(s + lane * 4);
  const float4 bv = *reinterpret_cast<const float4*>(b + lane * 4);
  float4 y;
  y.x = dx * inv * sv.x + bv.x;
  y.y = dy * inv * sv.y + bv.y;
  y.z = dz * inv * sv.z + bv.z;
  y.w = dw * inv * sv.w + bv.w;
  if (outf) *reinterpret_cast<float4*>(outf + (long)row * DD_ + lane * 4) = y;
  if (outb) {
    uint2 pk;
    pk.x = bfbits(y.x) | (bfbits(y.y) << 16);
    pk.y = bfbits(y.z) | (bfbits(y.w) << 16);
    *reinterpret_cast<uint2*>(outb + (long)row * DD_ + lane * 4) = pk;
  }
}

// ---- GEMM: C[M,N] = A[M,K](bf16) @ Wt[N,K]^T ----
// EPI 0: bf16 = acc+bias | 1: bf16 = relu | 2: f32 = resid+acc+bias
// EPI 3: qkv-mode: cols<512 -> bf16 to out[M,768]; cols>=512 -> scatter to vt[bh][64][1024]
template<int EPI>
__global__ __launch_bounds__(256)
void k_gemm(const bf16* __restrict__ A, const bf16* __restrict__ Wt,
            const float* __restrict__ bias, const float* __restrict__ resid,
            void* __restrict__ out, bf16* __restrict__ vt, int M, int N, int K) {
  __shared__ alignas(16) bf16 As[128 * 32];
  __shared__ alignas(16) bf16 Bs[128 * 32];
  const int t = threadIdx.x;
  const int lane = t & 63, wid = t >> 6;
  const int wr = wid >> 1, wc = wid & 1;
  const int mbase = blockIdx.y * 128, nbase = blockIdx.x * 128;
  const int g = lane >> 4, c = lane & 15;
  const int sr = t >> 2;
  const int sk = (t & 3) * 8;

  f32x4 acc[4][4] = {};

  const int nk = K >> 5;
  for (int kt = 0; kt < nk; ++kt) {
    const int k0 = kt * 32;
    int4 a0 = *reinterpret_cast<const int4*>(A + (long)(mbase + sr) * K + k0 + sk);
    int4 a1 = *reinterpret_cast<const int4*>(A + (long)(mbase + 64 + sr) * K + k0 + sk);
    int4 b0 = *reinterpret_cast<const int4*>(Wt + (long)(nbase + sr) * K + k0 + sk);
    int4 b1 = *reinterpret_cast<const int4*>(Wt + (long)(nbase + 64 + sr) * K + k0 + sk);
    __syncthreads();
    *reinterpret_cast<int4*>(As + sr * 32 + sk) = a0;
    *reinterpret_cast<int4*>(As + (64 + sr) * 32 + sk) = a1;
    *reinterpret_cast<int4*>(Bs + sr * 32 + sk) = b0;
    *reinterpret_cast<int4*>(Bs + (64 + sr) * 32 + sk) = b1;
    __syncthreads();

    bf16x8 af[4], bfr[4];
    #pragma unroll
    for (int mi = 0; mi < 4; mi++) af[mi]  = ld_bf8(As + (wr * 64 + mi * 16 + c) * 32 + g * 8);
    #pragma unroll
    for (int ni = 0; ni < 4; ni++) bfr[ni] = ld_bf8(Bs + (wc * 64 + ni * 16 + c) * 32 + g * 8);
    #pragma unroll
    for (int mi = 0; mi < 4; mi++)
      #pragma unroll
      for (int ni = 0; ni < 4; ni++)
        acc[mi][ni] = MFMA(af[mi], bfr[ni], acc[mi][ni]);
  }

  #pragma unroll
  for (int mi = 0; mi < 4; mi++) {
    #pragma unroll
    for (int ni = 0; ni < 4; ni++) {
      const int colg = nbase + wc * 64 + ni * 16 + c;
      const float bv = bias ? bias[colg] : 0.f;
      #pragma unroll
      for (int j = 0; j < 4; j++) {
        const int rowg = mbase + wr * 64 + mi * 16 + g * 4 + j;
        float v = acc[mi][ni][j] + bv;
        if constexpr (EPI == 0) {
          ((bf16*)out)[(long)rowg * N + colg] = (bf16)v;
        } else if constexpr (EPI == 1) {
          ((bf16*)out)[(long)rowg * N + colg] = (bf16)fmaxf(v, 0.f);
        } else if constexpr (EPI == 2) {
          float r = resid ? resid[(long)rowg * N + colg] : 0.f;
          ((float*)out)[(long)rowg * N + colg] = r + v;
        } else {
          if (nbase < 512) {
            ((bf16*)out)[(long)rowg * N + colg] = (bf16)v;
          } else {
            // v-region -> vt[(b*4+h)][d][t]
            const int dfull = colg - 512;
            const int hh = dfull >> 6, d = dfull & 63;
            const int bb = rowg >> 10, tl = rowg & 1023;
            vt[(long)((bb << 2) + hh) * 65536 + d * 1024 + tl] = (bf16)v;
          }
        }
      }
    }
  }
}

// ---- flash attention (swapped-QK^T, O^T accum, fully swizzled LDS) ----
// qkv: [MTOK][768] bf16 (q cols 0..255, k cols 256..511); vtg: [64 bh][64 d][1024 t]
__global__ __launch_bounds__(256)
void k_attn(const bf16* __restrict__ qkv, const bf16* __restrict__ vtg,
            bf16* __restrict__ o) {
  __shared__ alignas(16) char Ks[8192];   // [64 kv][64 d] swizzled
  __shared__ alignas(16) char Vs[8192];   // [64 d][64 kv] swizzled
  __shared__ alignas(16) char Ps[8192];   // per-wave [16 q][64 kv] swizzled
  const int t = threadIdx.x, lane = t & 63, w = t >> 6;
  const int g = lane >> 4, c = lane & 15;
  const int bh = blockIdx.y, b = bh >> 2, h = bh & 3;
  const int qt = blockIdx.x;
  const long tokbase = (long)b * TT;
  const float scale = 0.125f;
  const int q_glob = qt * 64 + w * 16 + c;

  // hoisted Q fragments: B[n=q=c][k=d = kk*32 + g*8 + i]
  bf16x8 qf0 = ld_bf8(qkv + (tokbase + q_glob) * 768 + h * 64 + g * 8);
  bf16x8 qf1 = ld_bf8(qkv + (tokbase + q_glob) * 768 + h * 64 + 32 + g * 8);

  const int sr = t >> 3;                // staging row 0..31
  const int scb = (t & 7) * 16;         // staging byte col
  const int swz_s = (sr & 7) << 4;
  const int swz_c = (c & 7) << 4;
  const bf16* kbase = qkv + 256 + h * 64 + (t & 7) * 8;
  const bf16* vbase = vtg + (long)bh * 65536 + (t & 7) * 8;
  char* pw = Ps + w * 2048 + c * 128;

  f32x4 oacc[4] = {};
  float mrun = -1e30f, lrun = 0.f;

  for (int jt = 0; jt < 16; ++jt) {
    int4 k0 = *reinterpret_cast<const int4*>(kbase + (tokbase + jt * 64 + sr) * 768);
    int4 k1 = *reinterpret_cast<const int4*>(kbase + (tokbase + jt * 64 + sr + 32) * 768);
    int4 v0 = *reinterpret_cast<const int4*>(vbase + (long)sr * 1024 + jt * 64);
    int4 v1 = *reinterpret_cast<const int4*>(vbase + (long)(sr + 32) * 1024 + jt * 64);
    __syncthreads();
    *reinterpret_cast<int4*>(Ks + sr * 128 + (scb ^ swz_s)) = k0;
    *reinterpret_cast<int4*>(Ks + (sr + 32) * 128 + (scb ^ swz_s)) = k1;
    *reinterpret_cast<int4*>(Vs + sr * 128 + (scb ^ swz_s)) = v0;
    *reinterpret_cast<int4*>(Vs + (sr + 32) * 128 + (scb ^ swz_s)) = v1;
    __syncthreads();

    // S^T = K · Q^T : C[kv][q], kv rows from Ks
    f32x4 sacc[4] = {};
    #pragma unroll
    for (int ni = 0; ni < 4; ni++) {
      const char* krow = Ks + (ni * 16 + c) * 128;
      bf16x8 kf0 = ld_bf8(krow + ((g * 16) ^ swz_c));
      bf16x8 kf1 = ld_bf8(krow + ((64 + g * 16) ^ swz_c));
      sacc[ni] = MFMA(kf0, qf0, sacc[ni]);
      sacc[ni] = MFMA(kf1, qf1, sacc[ni]);
    }

    // online softmax: lane owns q=c; kv values at ni*16 + g*4 + j
    float m0 = -1e30f;
    #pragma unroll
    for (int ni = 0; ni < 4; ni++)
      #pragma unroll
      for (int j = 0; j < 4; j++) m0 = fmaxf(m0, sacc[ni][j]);
    m0 = fmaxf(m0, __shfl_xor(m0, 16));
    m0 = fmaxf(m0, __shfl_xor(m0, 32));
    const float mn = fmaxf(mrun, m0);
    const float al = __expf(scale * (mrun - mn));
    mrun = mn;

    float rs = 0.f;
    unsigned pk[8];
    #pragma unroll
    for (int ni = 0; ni < 4; ni++) {
      float p0 = __expf(scale * (sacc[ni][0] - mn));
      float p1 = __expf(scale * (sacc[ni][1] - mn));
      float p2 = __expf(scale * (sacc[ni][2] - mn));
      float p3 = __expf(scale * (sacc[ni][3] - mn));
      rs += (p0 + p1) + (p2 + p3);
      pk[ni * 2]     = bfbits(p0) | (bfbits(p1) << 16);
      pk[ni * 2 + 1] = bfbits(p2) | (bfbits(p3) << 16);
    }
    rs += __shfl_xor(rs, 16);
    rs += __shfl_xor(rs, 32);
    lrun = lrun * al + rs;
    #pragma unroll
    for (int nd = 0; nd < 4; nd++)
      #pragma unroll
      for (int j = 0; j < 4; j++) oacc[nd][j] *= al;

    // write P quads (vectorized, swizzled, per-wave region -> no barrier)
    #pragma unroll
    for (int ni = 0; ni < 4; ni++) {
      uint2 q2; q2.x = pk[ni * 2]; q2.y = pk[ni * 2 + 1];
      *reinterpret_cast<uint2*>(pw + ((ni * 32 + g * 8) ^ swz_c)) = q2;
    }

    // O^T += V^T · P^T : A = Vs rows (d), B = P rows (q)
    #pragma unroll
    for (int kk = 0; kk < 2; kk++) {
      bf16x8 pf = ld_bf8(pw + ((kk * 64 + g * 16) ^ swz_c));
      #pragma unroll
      for (int nd = 0; nd < 4; nd++) {
        bf16x8 vf = ld_bf8(Vs + (nd * 16 + c) * 128 + ((kk * 64 + g * 16) ^ swz_c));
        oacc[nd] = MFMA(vf, pf, oacc[nd]);
      }
    }
  }

  const float inv = 1.f / lrun;
  bf16* orow = o + (tokbase + q_glob) * 256 + h * 64 + g * 4;
  #pragma unroll
  for (int nd = 0; nd < 4; nd++) {
    uint2 st;
    st.x = bfbits(oacc[nd][0] * inv) | (bfbits(oacc[nd][1] * inv) << 16);
    st.y = bfbits(oacc[nd][2] * inv) | (bfbits(oacc[nd][3] * inv) << 16);
    *reinterpret_cast<uint2*>(orow + nd * 16) = st;
  }
}

// ---- host ----
extern "C" void kernel_launch(void* const* d_in, const int* in_sizes, int n_in,
                              void* d_out, int out_size, void* d_ws, size_t ws_size,
                              hipStream_t stream) {
  const float* x     = (const float*)d_in[0];
  const float* Win   = (const float*)d_in[2];
  const float* b_in  = (const float*)d_in[3];
  const float* ln1_s = (const float*)d_in[4];
  const float* ln1_b = (const float*)d_in[5];
  const float* Wq    = (const float*)d_in[6];
  const float* bq    = (const float*)d_in[7];
  const float* Wk    = (const float*)d_in[8];
  const float* bk    = (const float*)d_in[9];
  const float* Wv    = (const float*)d_in[10];
  const float* bv    = (const float*)d_in[11];
  const float* Wo    = (const float*)d_in[12];
  const float* bo    = (const float*)d_in[13];
  const float* ln2_s = (const float*)d_in[14];
  const float* ln2_b = (const float*)d_in[15];
  const float* W1    = (const float*)d_in[16];
  const float* b1    = (const float*)d_in[17];
  const float* W2    = (const float*)d_in[18];
  const float* b2    = (const float*)d_in[19];
  const float* lno_s = (const float*)d_in[20];
  const float* lno_b = (const float*)d_in[21];
  float* out = (float*)d_out;

  char* ws = (char*)d_ws;
  size_t off = 0;
  auto alloc = [&](size_t bytes) -> void* {
    void* p = ws + off; off += (bytes + 255) & ~(size_t)255; return p;
  };
  float* e    = (float*)alloc((size_t)MTOK * DD_ * 4);
  bf16* e_bf  = (bf16*)alloc((size_t)MTOK * DD_ * 2);
  bf16* qkvb  = (bf16*)alloc((size_t)MTOK * 768 * 2);
  bf16* vtb   = (bf16*)alloc((size_t)MTOK * DD_ * 2);
  bf16* ob    = (bf16*)alloc((size_t)MTOK * DD_ * 2);
  bf16* hb    = (bf16*)alloc((size_t)MTOK * FF_ * 2);
  bf16* x_bf  = (bf16*)hb;   // alias: x_bf consumed before hb first written
  bf16* Wint  = (bf16*)alloc((size_t)DD_ * KPAD * 2);
  bf16* Wqkvt = (bf16*)alloc((size_t)LL * 768 * DD_ * 2);
  bf16* Wot   = (bf16*)alloc((size_t)LL * DD_ * DD_ * 2);
  bf16* W1t   = (bf16*)alloc((size_t)LL * DD_ * FF_ * 2);
  bf16* W2t   = (bf16*)alloc((size_t)LL * FF_ * DD_ * 2);
  float* bqkv = (float*)alloc((size_t)LL * 768 * 4);

  dim3 blk(256);

  // conversions
  k_convert_pad<<<(MTOK * KPAD + 255) / 256, 256, 0, stream>>>(x, x_bf, MTOK, IDIM_, KPAD);
  k_wt_convert<<<(DD_ * KPAD + 255) / 256, 256, 0, stream>>>(Win, Wint, IDIM_, DD_, KPAD);
  k_wt_all<<<dim3(1024, 24), blk, 0, stream>>>(Wq, Wk, Wv, Wo, W1, W2, Wqkvt, Wot, W1t, W2t);
  k_bias_concat<<<(LL * 768 + 255) / 256, 256, 0, stream>>>(bq, bk, bv, bqkv);

  // input projection: e = x @ Win + b_in  (f32 out)
  k_gemm<2><<<dim3(2, 128), blk, 0, stream>>>(x_bf, Wint, b_in, nullptr, e, nullptr, MTOK, DD_, KPAD);

  const long DDW = (long)DD_ * DD_;
  const long DFF = (long)DD_ * FF_;
  for (int i = 0; i < LL; i++) {
    k_ln<<<MTOK / 4, 256, 0, stream>>>(e, e, e_bf, ln1_s + i * DD_, ln1_b + i * DD_);
    // fused QKV (q,k -> qkvb; v -> vtb transposed per-head)
    k_gemm<3><<<dim3(6, 128), blk, 0, stream>>>(e_bf, Wqkvt + (long)i * 768 * DD_, bqkv + i * 768,
                                                nullptr, qkvb, vtb, MTOK, 768, DD_);
    k_attn<<<dim3(16, 64), blk, 0, stream>>>(qkvb, vtb, ob);
    k_gemm<2><<<dim3(2, 128), blk, 0, stream>>>(ob, Wot + i * DDW, bo + i * DD_, e, e, nullptr, MTOK, DD_, DD_);
    k_ln<<<MTOK / 4, 256, 0, stream>>>(e, e, e_bf, ln2_s + i * DD_, ln2_b + i * DD_);
    k_gemm<1><<<dim3(8, 128), blk, 0, stream>>>(e_bf, W1t + i * DFF, b1 + i * FF_, nullptr, hb, nullptr, MTOK, FF_, DD_);
    k_gemm<2><<<dim3(2, 128), blk, 0, stream>>>(hb, W2t + i * DFF, b2 + i * DD_, e, e, nullptr, MTOK, DD_, FF_);
  }
  k_ln<<<MTOK / 4, 256, 0, stream>>>(e, out, nullptr, lno_s, lno_b);
}